// Round 11
// baseline (148.399 us; speedup 1.0000x reference)
//
#include <hip/hip_runtime.h>
#include <hip/hip_bf16.h>
#include <math.h>

#define NN 256
#define CC 128
#define HH 4
#define DD 32

typedef uint4 u128;
typedef __bf16 bf16x8 __attribute__((ext_vector_type(8)));
typedef float f32x4 __attribute__((ext_vector_type(4)));

#define LOG2E 1.4426950408889634f
#define QSC (0.17677669529663687f * LOG2E)   // 1/sqrt(32) * log2(e), folded into q

// ---------------------------------------------------------------------------
// K0 prep: bias2 = PERMUTED bias layout so attn's per-lane bias loads are
//          fully coalesced (see attn kernel comment).
//          Wt_qkv[n][k] = bf16(Wqkv[k][n]); Wt_out[n][k] = bf16(Wout[k][n])
// ---------------------------------------------------------------------------
__global__ __launch_bounds__(256) void prep_kernel(
    const float* __restrict__ dm, const int* __restrict__ mask,
    const float* __restrict__ dscale,
    const float* __restrict__ Wqkv, const float* __restrict__ Wout,
    float* __restrict__ bias2,
    __hip_bfloat16* __restrict__ Wt_qkv, __hip_bfloat16* __restrict__ Wt_out)
{
    const int b = blockIdx.x, t = threadIdx.x;
    if (b < 256) {
        const int j = b, k = t;               // coalesced source read
        int idx = j * 256 + k;
        float v = mask[idx] ? -INFINITY : dscale[0] * dm[idx] * LOG2E;
        int c = k >> 5, bb = (k >> 4) & 1, quad = (k >> 2) & 3, r = k & 3;
        int dst = ((((c * 2 + bb) * 16 + (j >> 4)) * 64) + quad * 16 + (j & 15)) * 4 + r;
        bias2[dst] = v;
    } else if (b < 448) {
        int idx = (b - 256) * 256 + t;         // [0, 49152)
        int n = idx >> 7, k = idx & 127;
        Wt_qkv[idx] = __float2bfloat16(Wqkv[(size_t)k * 384 + n]);
    } else {
        int idx = (b - 448) * 256 + t;         // [0, 16384)
        int n = idx >> 7, k = idx & 127;
        Wt_out[idx] = __float2bfloat16(Wout[(size_t)k * CC + n]);
    }
}

// ---------------------------------------------------------------------------
// K1: qkv = pair_rep @ Wqkv + bqkv.  64-ROW TILES: grid 1024, LDS 42.9 KB
// (As[64][136] 17.4 + Bs[96][136] 25.5) -> 3 blocks/CU (was 2 at 59.5 KB),
// and the per-block serial staging chain halves. Waves 4m x 2n:
// mw=(w&3)*16 (one 16-row m-tile), nw=(w>>2)*48 (3 n-tiles). VGPR ~70
// (pf[4]+acc[3]+breg[3]) -> (512,6) cap 85 holds without spill.
// ---------------------------------------------------------------------------
__global__ __launch_bounds__(512, 6) void qkv_mfma_kernel(
    const float* __restrict__ A,              // [65536,128] fp32
    const __hip_bfloat16* __restrict__ Bt,    // [384,128] bf16 (transposed W)
    const float* __restrict__ bias,           // [384]
    __hip_bfloat16* __restrict__ out)         // [65536,384]
{
    __shared__ __align__(16) __hip_bfloat16 As[64][136];
    __shared__ __align__(16) __hip_bfloat16 Bs[96][136];
    const int t = threadIdx.x;
    const int m0 = blockIdx.x * 64;

    float4 va[4];
    #pragma unroll
    for (int it = 0; it < 4; ++it) {
        int idx = it * 512 + t;
        int r = idx >> 5, c4 = (idx & 31) * 4;
        va[it] = *(const float4*)(A + (size_t)(m0 + r) * CC + c4);
    }
    #pragma unroll
    for (int it = 0; it < 4; ++it) {
        int idx = it * 512 + t;
        int r = idx >> 5, c4 = (idx & 31) * 4;
        __hip_bfloat162 a01 = __float22bfloat162_rn(float2{va[it].x, va[it].y});
        __hip_bfloat162 a23 = __float22bfloat162_rn(float2{va[it].z, va[it].w});
        uint2 pk;
        pk.x = *(unsigned int*)&a01;
        pk.y = *(unsigned int*)&a23;
        *(uint2*)&As[r][c4] = pk;
    }
    #pragma unroll
    for (int it = 0; it < 3; ++it) {           // B chunk 0
        int idx = it * 512 + t;
        int n = idx >> 4, c8 = (idx & 15) * 8;
        *(u128*)&Bs[n][c8] = *(const u128*)(Bt + (size_t)n * CC + c8);
    }
    __syncthreads();

    const int w = t >> 6, lane = t & 63;
    const int n16 = lane & 15, quad = lane >> 4;
    const int mw = (w & 3) * 16, nw = (w >> 2) * 48;

    bf16x8 pf[4];                              // pair fragments — loaded once
    #pragma unroll
    for (int ks = 0; ks < 4; ++ks)
        pf[ks] = *(const bf16x8*)&As[mw + n16][ks * 32 + quad * 8];

    for (int nc = 0; nc < 4; ++nc) {
        const int n0 = nc * 96;

        f32x4 acc[3];
        #pragma unroll
        for (int nt = 0; nt < 3; ++nt) acc[nt] = (f32x4){0.f, 0.f, 0.f, 0.f};

        #pragma unroll
        for (int nt = 0; nt < 3; ++nt) {
            bf16x8 wf[4];
            #pragma unroll
            for (int ks = 0; ks < 4; ++ks)
                wf[ks] = *(const bf16x8*)&Bs[nw + nt * 16 + n16][ks * 32 + quad * 8];
            #pragma unroll
            for (int ks = 0; ks < 4; ++ks)
                acc[nt] = __builtin_amdgcn_mfma_f32_16x16x32_bf16(wf[ks], pf[ks], acc[nt], 0, 0, 0);
        }
        __syncthreads();                       // all waves done reading Bs

        u128 breg[3];
        if (nc < 3) {                          // issue next-chunk B loads NOW
            #pragma unroll
            for (int it = 0; it < 3; ++it) {
                int idx = it * 512 + t;
                int n = idx >> 4, c8 = (idx & 15) * 8;
                breg[it] = *(const u128*)(Bt + (size_t)(n0 + 96 + n) * CC + c8);
            }
        }

        #pragma unroll
        for (int nt = 0; nt < 3; ++nt) {
            int nbase = n0 + nw + nt * 16 + quad * 4;
            float4 b4 = *(const float4*)(bias + nbase);
            float sc = (nbase < CC) ? QSC : 1.0f;
            int m = m0 + mw + n16;
            __hip_bfloat162 h01 = __float22bfloat162_rn(float2{(acc[nt][0] + b4.x) * sc, (acc[nt][1] + b4.y) * sc});
            __hip_bfloat162 h23 = __float22bfloat162_rn(float2{(acc[nt][2] + b4.z) * sc, (acc[nt][3] + b4.w) * sc});
            uint2 pk;
            pk.x = *(unsigned int*)&h01;
            pk.y = *(unsigned int*)&h23;
            *(uint2*)&out[(size_t)m * 384 + nbase] = pk;
        }

        if (nc < 3) {
            #pragma unroll
            for (int it = 0; it < 3; ++it) {
                int idx = it * 512 + t;
                int n = idx >> 4, c8 = (idx & 15) * 8;
                *(u128*)&Bs[n][c8] = breg[it];
            }
            __syncthreads();
        }
    }
}

// ---------------------------------------------------------------------------
// K2: attention, TWO i per block (R10-proven). Block = (i-pair, h), grid 512.
//   Two independent MFMA->exp2->pack->PV chains per wave; shared bias2 loads
//   feed four S-MFMA C-operands; coalesced K/V staging. LDS 73 KB, 2 bl/CU.
// ---------------------------------------------------------------------------
__global__ __launch_bounds__(512, 4) void attn_mfma_kernel(
    const __hip_bfloat16* __restrict__ qkv,   // [65536,384]
    const float* __restrict__ bias2,          // [256,256] permuted, *log2e
    __hip_bfloat16* __restrict__ attn_out)    // [65536,128]
{
    __shared__ __align__(16) __hip_bfloat16 Ks[2][NN][40];   // 40.0 KB
    __shared__ __align__(16) __hip_bfloat16 VTs[2][DD][264]; // 33.0 KB

    const int bi = blockIdx.x;
    const int h = bi >> 7, ip = bi & 127;
    const int i0 = ip * 2;
    const int t = threadIdx.x;
    const int w = t >> 6, lane = t & 63;
    const int n16 = lane & 15, quad = lane >> 4;

    // ---- coalesced staging: idx -> (row, quarter) ------------------------
    #pragma unroll
    for (int ii = 0; ii < 2; ++ii) {
        const int i = i0 + ii;
        #pragma unroll
        for (int it = 0; it < 2; ++it) {
            int idx = it * 512 + t;            // 1024 = 256 rows x 4 quarters
            int row = idx >> 2, q4 = idx & 3;
            const __hip_bfloat16* base = qkv + ((size_t)i * NN + row) * 384 + h * DD;
            *(u128*)&Ks[ii][row][q4 * 8] = *(const u128*)(base + CC + q4 * 8);
            u128 vr = *(const u128*)(base + 2 * CC + q4 * 8);
            const __hip_bfloat16* vh = (const __hip_bfloat16*)&vr;
            // k-bit perm: row=[b4|q1q0|r1r0] -> pos=[q1q0|b4|r1r0]
            int pr = (row & ~0x1F) | ((row & 0xC) << 1) | ((row & 0x10) >> 2) | (row & 0x3);
            #pragma unroll
            for (int dd = 0; dd < 8; ++dd) VTs[ii][q4 * 8 + dd][pr] = vh[dd];
        }
    }
    __syncthreads();

    #pragma unroll
    for (int jt = 0; jt < 2; ++jt) {
        const int j0 = w * 32 + jt * 16;
        const int j = j0 + n16;                // this lane's softmax column
        const int jblk = w * 2 + jt;           // j0 >> 4

        bf16x8 qa0 = *(const bf16x8*)(qkv + ((size_t)i0 * NN + j) * 384 + h * DD + quad * 8);
        bf16x8 qa1 = *(const bf16x8*)(qkv + ((size_t)(i0 + 1) * NN + j) * 384 + h * DD + quad * 8);
        const float4* bb = (const float4*)bias2;

        f32x4 sm0 = {0.f, 0.f, 0.f, 0.f}, sm1 = {0.f, 0.f, 0.f, 0.f};
        f32x4 o00 = {0.f, 0.f, 0.f, 0.f}, o01 = {0.f, 0.f, 0.f, 0.f};
        f32x4 o10 = {0.f, 0.f, 0.f, 0.f}, o11 = {0.f, 0.f, 0.f, 0.f};

        #pragma unroll 2
        for (int c = 0; c < 8; ++c) {
            float4 b0 = bb[((c * 2 + 0) * 16 + jblk) * 64 + lane];
            float4 b1 = bb[((c * 2 + 1) * 16 + jblk) * 64 + lane];
            bf16x8 kb00 = *(const bf16x8*)&Ks[0][c * 32 + n16][quad * 8];
            bf16x8 kb01 = *(const bf16x8*)&Ks[0][c * 32 + 16 + n16][quad * 8];
            bf16x8 kb10 = *(const bf16x8*)&Ks[1][c * 32 + n16][quad * 8];
            bf16x8 kb11 = *(const bf16x8*)&Ks[1][c * 32 + 16 + n16][quad * 8];
            f32x4 s00 = __builtin_amdgcn_mfma_f32_16x16x32_bf16(
                kb00, qa0, (f32x4){b0.x, b0.y, b0.z, b0.w}, 0, 0, 0);
            f32x4 s01 = __builtin_amdgcn_mfma_f32_16x16x32_bf16(
                kb01, qa0, (f32x4){b1.x, b1.y, b1.z, b1.w}, 0, 0, 0);
            f32x4 s10 = __builtin_amdgcn_mfma_f32_16x16x32_bf16(
                kb10, qa1, (f32x4){b0.x, b0.y, b0.z, b0.w}, 0, 0, 0);
            f32x4 s11 = __builtin_amdgcn_mfma_f32_16x16x32_bf16(
                kb11, qa1, (f32x4){b1.x, b1.y, b1.z, b1.w}, 0, 0, 0);

            // chain 0 (i0)
            {
                float p0 = __builtin_amdgcn_exp2f(s00[0]);
                float p1 = __builtin_amdgcn_exp2f(s00[1]);
                float p2 = __builtin_amdgcn_exp2f(s00[2]);
                float p3 = __builtin_amdgcn_exp2f(s00[3]);
                float p4 = __builtin_amdgcn_exp2f(s01[0]);
                float p5 = __builtin_amdgcn_exp2f(s01[1]);
                float p6 = __builtin_amdgcn_exp2f(s01[2]);
                float p7 = __builtin_amdgcn_exp2f(s01[3]);
                sm0[0] += p0 + p4;
                sm0[1] += p1 + p5;
                sm0[2] += p2 + p6;
                sm0[3] += p3 + p7;
                __hip_bfloat162 q01 = __float22bfloat162_rn(float2{p0, p1});
                __hip_bfloat162 q23 = __float22bfloat162_rn(float2{p2, p3});
                __hip_bfloat162 q45 = __float22bfloat162_rn(float2{p4, p5});
                __hip_bfloat162 q67 = __float22bfloat162_rn(float2{p6, p7});
                u128 pk;
                pk.x = *(unsigned int*)&q01;
                pk.y = *(unsigned int*)&q23;
                pk.z = *(unsigned int*)&q45;
                pk.w = *(unsigned int*)&q67;
                bf16x8 pa = *(bf16x8*)&pk;
                bf16x8 vb0 = *(const bf16x8*)&VTs[0][n16][c * 32 + quad * 8];
                bf16x8 vb1 = *(const bf16x8*)&VTs[0][16 + n16][c * 32 + quad * 8];
                o00 = __builtin_amdgcn_mfma_f32_16x16x32_bf16(vb0, pa, o00, 0, 0, 0);
                o01 = __builtin_amdgcn_mfma_f32_16x16x32_bf16(vb1, pa, o01, 0, 0, 0);
            }
            // chain 1 (i1) — independent of chain 0
            {
                float p0 = __builtin_amdgcn_exp2f(s10[0]);
                float p1 = __builtin_amdgcn_exp2f(s10[1]);
                float p2 = __builtin_amdgcn_exp2f(s10[2]);
                float p3 = __builtin_amdgcn_exp2f(s10[3]);
                float p4 = __builtin_amdgcn_exp2f(s11[0]);
                float p5 = __builtin_amdgcn_exp2f(s11[1]);
                float p6 = __builtin_amdgcn_exp2f(s11[2]);
                float p7 = __builtin_amdgcn_exp2f(s11[3]);
                sm1[0] += p0 + p4;
                sm1[1] += p1 + p5;
                sm1[2] += p2 + p6;
                sm1[3] += p3 + p7;
                __hip_bfloat162 q01 = __float22bfloat162_rn(float2{p0, p1});
                __hip_bfloat162 q23 = __float22bfloat162_rn(float2{p2, p3});
                __hip_bfloat162 q45 = __float22bfloat162_rn(float2{p4, p5});
                __hip_bfloat162 q67 = __float22bfloat162_rn(float2{p6, p7});
                u128 pk;
                pk.x = *(unsigned int*)&q01;
                pk.y = *(unsigned int*)&q23;
                pk.z = *(unsigned int*)&q45;
                pk.w = *(unsigned int*)&q67;
                bf16x8 pa = *(bf16x8*)&pk;
                bf16x8 vb0 = *(const bf16x8*)&VTs[1][n16][c * 32 + quad * 8];
                bf16x8 vb1 = *(const bf16x8*)&VTs[1][16 + n16][c * 32 + quad * 8];
                o10 = __builtin_amdgcn_mfma_f32_16x16x32_bf16(vb0, pa, o10, 0, 0, 0);
                o11 = __builtin_amdgcn_mfma_f32_16x16x32_bf16(vb1, pa, o11, 0, 0, 0);
            }
        }

        float sum0 = (sm0[0] + sm0[1]) + (sm0[2] + sm0[3]);
        sum0 += __shfl_xor(sum0, 16);
        sum0 += __shfl_xor(sum0, 32);
        float inv0 = 1.0f / sum0;
        float sum1 = (sm1[0] + sm1[1]) + (sm1[2] + sm1[3]);
        sum1 += __shfl_xor(sum1, 16);
        sum1 += __shfl_xor(sum1, 32);
        float inv1 = 1.0f / sum1;

        __hip_bfloat16* ob0 = attn_out + ((size_t)i0 * NN + j) * CC + h * DD + quad * 4;
        __hip_bfloat16* ob1 = attn_out + ((size_t)(i0 + 1) * NN + j) * CC + h * DD + quad * 4;
        {
            __hip_bfloat162 h01 = __float22bfloat162_rn(float2{o00[0] * inv0, o00[1] * inv0});
            __hip_bfloat162 h23 = __float22bfloat162_rn(float2{o00[2] * inv0, o00[3] * inv0});
            uint2 pk; pk.x = *(unsigned int*)&h01; pk.y = *(unsigned int*)&h23;
            *(uint2*)(ob0) = pk;
        }
        {
            __hip_bfloat162 h01 = __float22bfloat162_rn(float2{o01[0] * inv0, o01[1] * inv0});
            __hip_bfloat162 h23 = __float22bfloat162_rn(float2{o01[2] * inv0, o01[3] * inv0});
            uint2 pk; pk.x = *(unsigned int*)&h01; pk.y = *(unsigned int*)&h23;
            *(uint2*)(ob0 + 16) = pk;
        }
        {
            __hip_bfloat162 h01 = __float22bfloat162_rn(float2{o10[0] * inv1, o10[1] * inv1});
            __hip_bfloat162 h23 = __float22bfloat162_rn(float2{o10[2] * inv1, o10[3] * inv1});
            uint2 pk; pk.x = *(unsigned int*)&h01; pk.y = *(unsigned int*)&h23;
            *(uint2*)(ob1) = pk;
        }
        {
            __hip_bfloat162 h01 = __float22bfloat162_rn(float2{o11[0] * inv1, o11[1] * inv1});
            __hip_bfloat162 h23 = __float22bfloat162_rn(float2{o11[2] * inv1, o11[3] * inv1});
            uint2 pk; pk.x = *(unsigned int*)&h01; pk.y = *(unsigned int*)&h23;
            *(uint2*)(ob1 + 16) = pk;
        }
    }
}

// ---------------------------------------------------------------------------
// K3: out = attn_out @ Wout + bout.  64-ROW TILES: grid 1024, LDS 52.2 KB
// (As[64][136] 17.4 + Bs[128][136] 34.8) -> 3 blocks/CU (was 2 at 68 KB),
// per-block staging chain halves. Waves 4m x 2n: mw=(w&3)*16, nw=(w>>2)*64,
// pf[4] + acc[4] -> VGPR ~70, (512,6) cap 85 holds.
// ---------------------------------------------------------------------------
__global__ __launch_bounds__(512, 6) void out_mfma_kernel(
    const __hip_bfloat16* __restrict__ A,     // [65536,128] bf16
    const __hip_bfloat16* __restrict__ Bt,    // [128,128] bf16 (transposed W)
    const float* __restrict__ bias,           // [128]
    float* __restrict__ out)                  // [65536,128]
{
    __shared__ __align__(16) __hip_bfloat16 As[64][136];
    __shared__ __align__(16) __hip_bfloat16 Bs[128][136];
    const int t = threadIdx.x;
    const int m0 = blockIdx.x * 64;

    u128 ra[2], rb[4];
    #pragma unroll
    for (int it = 0; it < 2; ++it) {
        int idx = it * 512 + t;
        int r = idx >> 4, c8 = (idx & 15) * 8;
        ra[it] = *(const u128*)(A + (size_t)(m0 + r) * CC + c8);
    }
    #pragma unroll
    for (int it = 0; it < 4; ++it) {
        int idx = it * 512 + t;
        int n = idx >> 4, c8 = (idx & 15) * 8;
        rb[it] = *(const u128*)(Bt + (size_t)n * CC + c8);
    }
    #pragma unroll
    for (int it = 0; it < 2; ++it) {
        int idx = it * 512 + t;
        int r = idx >> 4, c8 = (idx & 15) * 8;
        *(u128*)&As[r][c8] = ra[it];
    }
    #pragma unroll
    for (int it = 0; it < 4; ++it) {
        int idx = it * 512 + t;
        int n = idx >> 4, c8 = (idx & 15) * 8;
        *(u128*)&Bs[n][c8] = rb[it];
    }
    __syncthreads();

    const int w = t >> 6, lane = t & 63;
    const int n16 = lane & 15, quad = lane >> 4;
    const int mw = (w & 3) * 16, nw = (w >> 2) * 64;

    bf16x8 pf[4];
    #pragma unroll
    for (int ks = 0; ks < 4; ++ks)
        pf[ks] = *(const bf16x8*)&As[mw + n16][ks * 32 + quad * 8];

    f32x4 acc[4];
    #pragma unroll
    for (int nt = 0; nt < 4; ++nt) acc[nt] = (f32x4){0.f, 0.f, 0.f, 0.f};

    #pragma unroll
    for (int nt = 0; nt < 4; ++nt) {
        bf16x8 wf[4];
        #pragma unroll
        for (int ks = 0; ks < 4; ++ks)
            wf[ks] = *(const bf16x8*)&Bs[nw + nt * 16 + n16][ks * 32 + quad * 8];
        #pragma unroll
        for (int ks = 0; ks < 4; ++ks)
            acc[nt] = __builtin_amdgcn_mfma_f32_16x16x32_bf16(wf[ks], pf[ks], acc[nt], 0, 0, 0);
    }

    #pragma unroll
    for (int nt = 0; nt < 4; ++nt) {
        int nbase = nw + nt * 16 + quad * 4;
        float4 b4 = *(const float4*)(bias + nbase);
        int m = m0 + mw + n16;
        float4 ov;
        ov.x = acc[nt][0] + b4.x;
        ov.y = acc[nt][1] + b4.y;
        ov.z = acc[nt][2] + b4.z;
        ov.w = acc[nt][3] + b4.w;
        *(float4*)&out[(size_t)m * CC + nbase] = ov;
    }
}

// ---------------------------------------------------------------------------
extern "C" void kernel_launch(void* const* d_in, const int* in_sizes, int n_in,
                              void* d_out, int out_size, void* d_ws, size_t ws_size,
                              hipStream_t stream) {
    const float* pair_rep = (const float*)d_in[0];
    const float* dm       = (const float*)d_in[1];
    const float* Wqkv     = (const float*)d_in[2];
    const float* bqkv     = (const float*)d_in[3];
    const float* Wout     = (const float*)d_in[4];
    const float* bout     = (const float*)d_in[5];
    const float* dscale   = (const float*)d_in[6];
    const int*   mask     = (const int*)d_in[7];
    float* out = (float*)d_out;

    // ws: bias2[256KB] | Wt_qkv[96KB] | Wt_out[32KB] | qkv[48MB] | attn[16MB]
    char* p = (char*)d_ws;
    float* bias2 = (float*)p;                 p += (size_t)NN * NN * 4;
    __hip_bfloat16* Wt_qkv = (__hip_bfloat16*)p;  p += (size_t)384 * CC * 2;
    __hip_bfloat16* Wt_out = (__hip_bfloat16*)p;  p += (size_t)CC * CC * 2;
    __hip_bfloat16* qkv  = (__hip_bfloat16*)p;    p += (size_t)65536 * 384 * 2;
    __hip_bfloat16* attn = (__hip_bfloat16*)p;

    prep_kernel<<<dim3(512), dim3(256), 0, stream>>>(dm, mask, dscale, Wqkv, Wout, bias2, Wt_qkv, Wt_out);
    qkv_mfma_kernel<<<dim3(1024), dim3(512), 0, stream>>>(pair_rep, Wt_qkv, bqkv, qkv);
    attn_mfma_kernel<<<dim3(512), dim3(512), 0, stream>>>(qkv, bias2, attn);
    out_mfma_kernel<<<dim3(1024), dim3(512), 0, stream>>>(attn, Wt_out, bout, out);
}

// Round 12
// 140.480 us; speedup vs baseline: 1.0564x; 1.0564x over previous
//
#include <hip/hip_runtime.h>
#include <hip/hip_bf16.h>
#include <math.h>

#define NN 256
#define CC 128
#define HH 4
#define DD 32

typedef uint4 u128;
typedef __bf16 bf16x8 __attribute__((ext_vector_type(8)));
typedef float f32x4 __attribute__((ext_vector_type(4)));

#define LOG2E 1.4426950408889634f
#define QSC (0.17677669529663687f * LOG2E)   // 1/sqrt(32) * log2(e), folded into q

// ---------------------------------------------------------------------------
// K0 prep: bias2 = PERMUTED bias layout so attn's per-lane bias loads are
//          fully coalesced (see attn kernel comment).
//          Wt_qkv[n][k] = bf16(Wqkv[k][n]); Wt_out[n][k] = bf16(Wout[k][n])
// ---------------------------------------------------------------------------
__global__ __launch_bounds__(256) void prep_kernel(
    const float* __restrict__ dm, const int* __restrict__ mask,
    const float* __restrict__ dscale,
    const float* __restrict__ Wqkv, const float* __restrict__ Wout,
    float* __restrict__ bias2,
    __hip_bfloat16* __restrict__ Wt_qkv, __hip_bfloat16* __restrict__ Wt_out)
{
    const int b = blockIdx.x, t = threadIdx.x;
    if (b < 256) {
        const int j = b, k = t;               // coalesced source read
        int idx = j * 256 + k;
        float v = mask[idx] ? -INFINITY : dscale[0] * dm[idx] * LOG2E;
        int c = k >> 5, bb = (k >> 4) & 1, quad = (k >> 2) & 3, r = k & 3;
        int dst = ((((c * 2 + bb) * 16 + (j >> 4)) * 64) + quad * 16 + (j & 15)) * 4 + r;
        bias2[dst] = v;
    } else if (b < 448) {
        int idx = (b - 256) * 256 + t;         // [0, 49152)
        int n = idx >> 7, k = idx & 127;
        Wt_qkv[idx] = __float2bfloat16(Wqkv[(size_t)k * 384 + n]);
    } else {
        int idx = (b - 448) * 256 + t;         // [0, 16384)
        int n = idx >> 7, k = idx & 127;
        Wt_out[idx] = __float2bfloat16(Wout[(size_t)k * CC + n]);
    }
}

// ---------------------------------------------------------------------------
// K1: qkv = pair_rep @ Wqkv + bqkv  (R6/R10-proven 128-row single-pass).
// Grid 512; A staged ONCE (batched loads), internal loop over the 4 96-col
// B chunks with prefetch-before-epilogue. LDS 59.5 KB, 2 blocks/CU.
// (R11's 64-row variant regressed: halving the tile kept per-block B-staging
// constant while doubling the grid -> staging:compute ratio worsened.)
// ---------------------------------------------------------------------------
__global__ __launch_bounds__(512, 2) void qkv_mfma_kernel(
    const float* __restrict__ A,              // [65536,128] fp32
    const __hip_bfloat16* __restrict__ Bt,    // [384,128] bf16 (transposed W)
    const float* __restrict__ bias,           // [384]
    __hip_bfloat16* __restrict__ out)         // [65536,384]
{
    __shared__ __align__(16) __hip_bfloat16 As[128][136];
    __shared__ __align__(16) __hip_bfloat16 Bs[96][136];
    const int t = threadIdx.x;
    const int m0 = blockIdx.x * 128;

    float4 va[8];
    #pragma unroll
    for (int it = 0; it < 8; ++it) {
        int idx = it * 512 + t;
        int r = idx >> 5, c4 = (idx & 31) * 4;
        va[it] = *(const float4*)(A + (size_t)(m0 + r) * CC + c4);
    }
    #pragma unroll
    for (int it = 0; it < 8; ++it) {
        int idx = it * 512 + t;
        int r = idx >> 5, c4 = (idx & 31) * 4;
        __hip_bfloat162 a01 = __float22bfloat162_rn(float2{va[it].x, va[it].y});
        __hip_bfloat162 a23 = __float22bfloat162_rn(float2{va[it].z, va[it].w});
        uint2 pk;
        pk.x = *(unsigned int*)&a01;
        pk.y = *(unsigned int*)&a23;
        *(uint2*)&As[r][c4] = pk;
    }
    #pragma unroll
    for (int it = 0; it < 3; ++it) {           // B chunk 0
        int idx = it * 512 + t;
        int n = idx >> 4, c8 = (idx & 15) * 8;
        *(u128*)&Bs[n][c8] = *(const u128*)(Bt + (size_t)n * CC + c8);
    }
    __syncthreads();

    const int w = t >> 6, lane = t & 63;
    const int n16 = lane & 15, quad = lane >> 4;
    const int mw = (w & 3) * 32, nw = (w >> 2) * 48;

    bf16x8 pf[2][4];                           // pair fragments — loaded once
    #pragma unroll
    for (int mt = 0; mt < 2; ++mt)
        #pragma unroll
        for (int ks = 0; ks < 4; ++ks)
            pf[mt][ks] = *(const bf16x8*)&As[mw + mt * 16 + n16][ks * 32 + quad * 8];

    for (int nc = 0; nc < 4; ++nc) {
        const int n0 = nc * 96;

        f32x4 acc[2][3];
        #pragma unroll
        for (int mt = 0; mt < 2; ++mt)
            #pragma unroll
            for (int nt = 0; nt < 3; ++nt) acc[mt][nt] = (f32x4){0.f, 0.f, 0.f, 0.f};

        #pragma unroll
        for (int nt = 0; nt < 3; ++nt) {
            bf16x8 wf[4];
            #pragma unroll
            for (int ks = 0; ks < 4; ++ks)
                wf[ks] = *(const bf16x8*)&Bs[nw + nt * 16 + n16][ks * 32 + quad * 8];
            #pragma unroll
            for (int ks = 0; ks < 4; ++ks)
                #pragma unroll
                for (int mt = 0; mt < 2; ++mt)
                    acc[mt][nt] = __builtin_amdgcn_mfma_f32_16x16x32_bf16(wf[ks], pf[mt][ks], acc[mt][nt], 0, 0, 0);
        }
        __syncthreads();                       // all waves done reading Bs

        u128 breg[3];
        if (nc < 3) {                          // issue next-chunk B loads NOW
            #pragma unroll
            for (int it = 0; it < 3; ++it) {
                int idx = it * 512 + t;
                int n = idx >> 4, c8 = (idx & 15) * 8;
                breg[it] = *(const u128*)(Bt + (size_t)(n0 + 96 + n) * CC + c8);
            }
        }

        #pragma unroll
        for (int nt = 0; nt < 3; ++nt) {
            int nbase = n0 + nw + nt * 16 + quad * 4;
            float4 b4 = *(const float4*)(bias + nbase);
            float sc = (nbase < CC) ? QSC : 1.0f;
            #pragma unroll
            for (int mt = 0; mt < 2; ++mt) {
                int m = m0 + mw + mt * 16 + n16;
                __hip_bfloat162 h01 = __float22bfloat162_rn(float2{(acc[mt][nt][0] + b4.x) * sc, (acc[mt][nt][1] + b4.y) * sc});
                __hip_bfloat162 h23 = __float22bfloat162_rn(float2{(acc[mt][nt][2] + b4.z) * sc, (acc[mt][nt][3] + b4.w) * sc});
                uint2 pk;
                pk.x = *(unsigned int*)&h01;
                pk.y = *(unsigned int*)&h23;
                *(uint2*)&out[(size_t)m * 384 + nbase] = pk;
            }
        }

        if (nc < 3) {
            #pragma unroll
            for (int it = 0; it < 3; ++it) {
                int idx = it * 512 + t;
                int n = idx >> 4, c8 = (idx & 15) * 8;
                *(u128*)&Bs[n][c8] = breg[it];
            }
            __syncthreads();
        }
    }
}

// ---------------------------------------------------------------------------
// K2: attention, TWO i per block (R10) + two latency fixes:
//   (1) depth-1 bias prefetch: c+1's two float4s issue at the top of iter c,
//       so the L2 round (~200cy) hides under this iter's MFMA+exp2+PV instead
//       of heading the dependent chain. +16 VGPR, cap 128, no spill.
//   (2) s_setprio(1) around the S-MFMA and PV-MFMA clusters (T5): waves at
//       different phases on the CU -> scheduler favors the MFMA-issuing wave.
// ---------------------------------------------------------------------------
__global__ __launch_bounds__(512, 4) void attn_mfma_kernel(
    const __hip_bfloat16* __restrict__ qkv,   // [65536,384]
    const float* __restrict__ bias2,          // [256,256] permuted, *log2e
    __hip_bfloat16* __restrict__ attn_out)    // [65536,128]
{
    __shared__ __align__(16) __hip_bfloat16 Ks[2][NN][40];   // 40.0 KB
    __shared__ __align__(16) __hip_bfloat16 VTs[2][DD][264]; // 33.0 KB

    const int bi = blockIdx.x;
    const int h = bi >> 7, ip = bi & 127;
    const int i0 = ip * 2;
    const int t = threadIdx.x;
    const int w = t >> 6, lane = t & 63;
    const int n16 = lane & 15, quad = lane >> 4;

    // ---- coalesced staging: idx -> (row, quarter) ------------------------
    #pragma unroll
    for (int ii = 0; ii < 2; ++ii) {
        const int i = i0 + ii;
        #pragma unroll
        for (int it = 0; it < 2; ++it) {
            int idx = it * 512 + t;            // 1024 = 256 rows x 4 quarters
            int row = idx >> 2, q4 = idx & 3;
            const __hip_bfloat16* base = qkv + ((size_t)i * NN + row) * 384 + h * DD;
            *(u128*)&Ks[ii][row][q4 * 8] = *(const u128*)(base + CC + q4 * 8);
            u128 vr = *(const u128*)(base + 2 * CC + q4 * 8);
            const __hip_bfloat16* vh = (const __hip_bfloat16*)&vr;
            // k-bit perm: row=[b4|q1q0|r1r0] -> pos=[q1q0|b4|r1r0]
            int pr = (row & ~0x1F) | ((row & 0xC) << 1) | ((row & 0x10) >> 2) | (row & 0x3);
            #pragma unroll
            for (int dd = 0; dd < 8; ++dd) VTs[ii][q4 * 8 + dd][pr] = vh[dd];
        }
    }
    __syncthreads();

    #pragma unroll
    for (int jt = 0; jt < 2; ++jt) {
        const int j0 = w * 32 + jt * 16;
        const int j = j0 + n16;                // this lane's softmax column
        const int jblk = w * 2 + jt;           // j0 >> 4

        bf16x8 qa0 = *(const bf16x8*)(qkv + ((size_t)i0 * NN + j) * 384 + h * DD + quad * 8);
        bf16x8 qa1 = *(const bf16x8*)(qkv + ((size_t)(i0 + 1) * NN + j) * 384 + h * DD + quad * 8);
        const float4* bb = (const float4*)bias2;

        f32x4 sm0 = {0.f, 0.f, 0.f, 0.f}, sm1 = {0.f, 0.f, 0.f, 0.f};
        f32x4 o00 = {0.f, 0.f, 0.f, 0.f}, o01 = {0.f, 0.f, 0.f, 0.f};
        f32x4 o10 = {0.f, 0.f, 0.f, 0.f}, o11 = {0.f, 0.f, 0.f, 0.f};

        // depth-1 bias software pipeline
        float4 b0 = bb[((0 * 2 + 0) * 16 + jblk) * 64 + lane];
        float4 b1 = bb[((0 * 2 + 1) * 16 + jblk) * 64 + lane];

        #pragma unroll 2
        for (int c = 0; c < 8; ++c) {
            float4 nb0, nb1;
            if (c < 7) {                       // issue next-iter bias NOW
                nb0 = bb[(((c + 1) * 2 + 0) * 16 + jblk) * 64 + lane];
                nb1 = bb[(((c + 1) * 2 + 1) * 16 + jblk) * 64 + lane];
            }

            bf16x8 kb00 = *(const bf16x8*)&Ks[0][c * 32 + n16][quad * 8];
            bf16x8 kb01 = *(const bf16x8*)&Ks[0][c * 32 + 16 + n16][quad * 8];
            bf16x8 kb10 = *(const bf16x8*)&Ks[1][c * 32 + n16][quad * 8];
            bf16x8 kb11 = *(const bf16x8*)&Ks[1][c * 32 + 16 + n16][quad * 8];
            __builtin_amdgcn_s_setprio(1);
            f32x4 s00 = __builtin_amdgcn_mfma_f32_16x16x32_bf16(
                kb00, qa0, (f32x4){b0.x, b0.y, b0.z, b0.w}, 0, 0, 0);
            f32x4 s01 = __builtin_amdgcn_mfma_f32_16x16x32_bf16(
                kb01, qa0, (f32x4){b1.x, b1.y, b1.z, b1.w}, 0, 0, 0);
            f32x4 s10 = __builtin_amdgcn_mfma_f32_16x16x32_bf16(
                kb10, qa1, (f32x4){b0.x, b0.y, b0.z, b0.w}, 0, 0, 0);
            f32x4 s11 = __builtin_amdgcn_mfma_f32_16x16x32_bf16(
                kb11, qa1, (f32x4){b1.x, b1.y, b1.z, b1.w}, 0, 0, 0);
            __builtin_amdgcn_s_setprio(0);

            // chain 0 (i0)
            {
                float p0 = __builtin_amdgcn_exp2f(s00[0]);
                float p1 = __builtin_amdgcn_exp2f(s00[1]);
                float p2 = __builtin_amdgcn_exp2f(s00[2]);
                float p3 = __builtin_amdgcn_exp2f(s00[3]);
                float p4 = __builtin_amdgcn_exp2f(s01[0]);
                float p5 = __builtin_amdgcn_exp2f(s01[1]);
                float p6 = __builtin_amdgcn_exp2f(s01[2]);
                float p7 = __builtin_amdgcn_exp2f(s01[3]);
                sm0[0] += p0 + p4;
                sm0[1] += p1 + p5;
                sm0[2] += p2 + p6;
                sm0[3] += p3 + p7;
                __hip_bfloat162 q01 = __float22bfloat162_rn(float2{p0, p1});
                __hip_bfloat162 q23 = __float22bfloat162_rn(float2{p2, p3});
                __hip_bfloat162 q45 = __float22bfloat162_rn(float2{p4, p5});
                __hip_bfloat162 q67 = __float22bfloat162_rn(float2{p6, p7});
                u128 pk;
                pk.x = *(unsigned int*)&q01;
                pk.y = *(unsigned int*)&q23;
                pk.z = *(unsigned int*)&q45;
                pk.w = *(unsigned int*)&q67;
                bf16x8 pa = *(bf16x8*)&pk;
                bf16x8 vb0 = *(const bf16x8*)&VTs[0][n16][c * 32 + quad * 8];
                bf16x8 vb1 = *(const bf16x8*)&VTs[0][16 + n16][c * 32 + quad * 8];
                __builtin_amdgcn_s_setprio(1);
                o00 = __builtin_amdgcn_mfma_f32_16x16x32_bf16(vb0, pa, o00, 0, 0, 0);
                o01 = __builtin_amdgcn_mfma_f32_16x16x32_bf16(vb1, pa, o01, 0, 0, 0);
                __builtin_amdgcn_s_setprio(0);
            }
            // chain 1 (i1) — independent of chain 0
            {
                float p0 = __builtin_amdgcn_exp2f(s10[0]);
                float p1 = __builtin_amdgcn_exp2f(s10[1]);
                float p2 = __builtin_amdgcn_exp2f(s10[2]);
                float p3 = __builtin_amdgcn_exp2f(s10[3]);
                float p4 = __builtin_amdgcn_exp2f(s11[0]);
                float p5 = __builtin_amdgcn_exp2f(s11[1]);
                float p6 = __builtin_amdgcn_exp2f(s11[2]);
                float p7 = __builtin_amdgcn_exp2f(s11[3]);
                sm1[0] += p0 + p4;
                sm1[1] += p1 + p5;
                sm1[2] += p2 + p6;
                sm1[3] += p3 + p7;
                __hip_bfloat162 q01 = __float22bfloat162_rn(float2{p0, p1});
                __hip_bfloat162 q23 = __float22bfloat162_rn(float2{p2, p3});
                __hip_bfloat162 q45 = __float22bfloat162_rn(float2{p4, p5});
                __hip_bfloat162 q67 = __float22bfloat162_rn(float2{p6, p7});
                u128 pk;
                pk.x = *(unsigned int*)&q01;
                pk.y = *(unsigned int*)&q23;
                pk.z = *(unsigned int*)&q45;
                pk.w = *(unsigned int*)&q67;
                bf16x8 pa = *(bf16x8*)&pk;
                bf16x8 vb0 = *(const bf16x8*)&VTs[1][n16][c * 32 + quad * 8];
                bf16x8 vb1 = *(const bf16x8*)&VTs[1][16 + n16][c * 32 + quad * 8];
                __builtin_amdgcn_s_setprio(1);
                o10 = __builtin_amdgcn_mfma_f32_16x16x32_bf16(vb0, pa, o10, 0, 0, 0);
                o11 = __builtin_amdgcn_mfma_f32_16x16x32_bf16(vb1, pa, o11, 0, 0, 0);
                __builtin_amdgcn_s_setprio(0);
            }

            if (c < 7) { b0 = nb0; b1 = nb1; }
        }

        float sum0 = (sm0[0] + sm0[1]) + (sm0[2] + sm0[3]);
        sum0 += __shfl_xor(sum0, 16);
        sum0 += __shfl_xor(sum0, 32);
        float inv0 = 1.0f / sum0;
        float sum1 = (sm1[0] + sm1[1]) + (sm1[2] + sm1[3]);
        sum1 += __shfl_xor(sum1, 16);
        sum1 += __shfl_xor(sum1, 32);
        float inv1 = 1.0f / sum1;

        __hip_bfloat16* ob0 = attn_out + ((size_t)i0 * NN + j) * CC + h * DD + quad * 4;
        __hip_bfloat16* ob1 = attn_out + ((size_t)(i0 + 1) * NN + j) * CC + h * DD + quad * 4;
        {
            __hip_bfloat162 h01 = __float22bfloat162_rn(float2{o00[0] * inv0, o00[1] * inv0});
            __hip_bfloat162 h23 = __float22bfloat162_rn(float2{o00[2] * inv0, o00[3] * inv0});
            uint2 pk; pk.x = *(unsigned int*)&h01; pk.y = *(unsigned int*)&h23;
            *(uint2*)(ob0) = pk;
        }
        {
            __hip_bfloat162 h01 = __float22bfloat162_rn(float2{o01[0] * inv0, o01[1] * inv0});
            __hip_bfloat162 h23 = __float22bfloat162_rn(float2{o01[2] * inv0, o01[3] * inv0});
            uint2 pk; pk.x = *(unsigned int*)&h01; pk.y = *(unsigned int*)&h23;
            *(uint2*)(ob0 + 16) = pk;
        }
        {
            __hip_bfloat162 h01 = __float22bfloat162_rn(float2{o10[0] * inv1, o10[1] * inv1});
            __hip_bfloat162 h23 = __float22bfloat162_rn(float2{o10[2] * inv1, o10[3] * inv1});
            uint2 pk; pk.x = *(unsigned int*)&h01; pk.y = *(unsigned int*)&h23;
            *(uint2*)(ob1) = pk;
        }
        {
            __hip_bfloat162 h01 = __float22bfloat162_rn(float2{o11[0] * inv1, o11[1] * inv1});
            __hip_bfloat162 h23 = __float22bfloat162_rn(float2{o11[2] * inv1, o11[3] * inv1});
            uint2 pk; pk.x = *(unsigned int*)&h01; pk.y = *(unsigned int*)&h23;
            *(uint2*)(ob1 + 16) = pk;
        }
    }
}

// ---------------------------------------------------------------------------
// K3: out = attn_out @ Wout + bout  (R6/R10-proven batched-LDS 128-row).
// ---------------------------------------------------------------------------
__global__ __launch_bounds__(512, 4) void out_mfma_kernel(
    const __hip_bfloat16* __restrict__ A,     // [65536,128] bf16
    const __hip_bfloat16* __restrict__ Bt,    // [128,128] bf16 (transposed W)
    const float* __restrict__ bias,           // [128]
    float* __restrict__ out)                  // [65536,128]
{
    __shared__ __align__(16) __hip_bfloat16 As[128][136];
    __shared__ __align__(16) __hip_bfloat16 Bs[128][136];
    const int t = threadIdx.x;
    const int m0 = blockIdx.x * 128;

    u128 ra[4], rb[4];
    #pragma unroll
    for (int it = 0; it < 4; ++it) {
        int idx = it * 512 + t;
        int r = idx >> 4, c8 = (idx & 15) * 8;
        ra[it] = *(const u128*)(A + (size_t)(m0 + r) * CC + c8);
    }
    #pragma unroll
    for (int it = 0; it < 4; ++it) {
        int idx = it * 512 + t;
        int n = idx >> 4, c8 = (idx & 15) * 8;
        rb[it] = *(const u128*)(Bt + (size_t)n * CC + c8);
    }
    #pragma unroll
    for (int it = 0; it < 4; ++it) {
        int idx = it * 512 + t;
        int r = idx >> 4, c8 = (idx & 15) * 8;
        *(u128*)&As[r][c8] = ra[it];
    }
    #pragma unroll
    for (int it = 0; it < 4; ++it) {
        int idx = it * 512 + t;
        int n = idx >> 4, c8 = (idx & 15) * 8;
        *(u128*)&Bs[n][c8] = rb[it];
    }
    __syncthreads();

    const int w = t >> 6, lane = t & 63;
    const int n16 = lane & 15, quad = lane >> 4;
    const int mw = (w & 3) * 32, nw = (w >> 2) * 64;

    bf16x8 pf[2][4];
    #pragma unroll
    for (int mt = 0; mt < 2; ++mt)
        #pragma unroll
        for (int ks = 0; ks < 4; ++ks)
            pf[mt][ks] = *(const bf16x8*)&As[mw + mt * 16 + n16][ks * 32 + quad * 8];

    f32x4 acc[2][4];
    #pragma unroll
    for (int mt = 0; mt < 2; ++mt)
        #pragma unroll
        for (int nt = 0; nt < 4; ++nt) acc[mt][nt] = (f32x4){0.f, 0.f, 0.f, 0.f};

    #pragma unroll
    for (int nt = 0; nt < 4; ++nt) {
        bf16x8 wf[4];
        #pragma unroll
        for (int ks = 0; ks < 4; ++ks)
            wf[ks] = *(const bf16x8*)&Bs[nw + nt * 16 + n16][ks * 32 + quad * 8];
        #pragma unroll
        for (int ks = 0; ks < 4; ++ks)
            #pragma unroll
            for (int mt = 0; mt < 2; ++mt)
                acc[mt][nt] = __builtin_amdgcn_mfma_f32_16x16x32_bf16(wf[ks], pf[mt][ks], acc[mt][nt], 0, 0, 0);
    }

    #pragma unroll
    for (int nt = 0; nt < 4; ++nt) {
        int nbase = nw + nt * 16 + quad * 4;
        float4 b4 = *(const float4*)(bias + nbase);
        #pragma unroll
        for (int mt = 0; mt < 2; ++mt) {
            int m = m0 + mw + mt * 16 + n16;
            float4 ov;
            ov.x = acc[mt][nt][0] + b4.x;
            ov.y = acc[mt][nt][1] + b4.y;
            ov.z = acc[mt][nt][2] + b4.z;
            ov.w = acc[mt][nt][3] + b4.w;
            *(float4*)&out[(size_t)m * CC + nbase] = ov;
        }
    }
}

// ---------------------------------------------------------------------------
extern "C" void kernel_launch(void* const* d_in, const int* in_sizes, int n_in,
                              void* d_out, int out_size, void* d_ws, size_t ws_size,
                              hipStream_t stream) {
    const float* pair_rep = (const float*)d_in[0];
    const float* dm       = (const float*)d_in[1];
    const float* Wqkv     = (const float*)d_in[2];
    const float* bqkv     = (const float*)d_in[3];
    const float* Wout     = (const float*)d_in[4];
    const float* bout     = (const float*)d_in[5];
    const float* dscale   = (const float*)d_in[6];
    const int*   mask     = (const int*)d_in[7];
    float* out = (float*)d_out;

    // ws: bias2[256KB] | Wt_qkv[96KB] | Wt_out[32KB] | qkv[48MB] | attn[16MB]
    char* p = (char*)d_ws;
    float* bias2 = (float*)p;                 p += (size_t)NN * NN * 4;
    __hip_bfloat16* Wt_qkv = (__hip_bfloat16*)p;  p += (size_t)384 * CC * 2;
    __hip_bfloat16* Wt_out = (__hip_bfloat16*)p;  p += (size_t)CC * CC * 2;
    __hip_bfloat16* qkv  = (__hip_bfloat16*)p;    p += (size_t)65536 * 384 * 2;
    __hip_bfloat16* attn = (__hip_bfloat16*)p;

    prep_kernel<<<dim3(512), dim3(256), 0, stream>>>(dm, mask, dscale, Wqkv, Wout, bias2, Wt_qkv, Wt_out);
    qkv_mfma_kernel<<<dim3(512), dim3(512), 0, stream>>>(pair_rep, Wt_qkv, bqkv, qkv);
    attn_mfma_kernel<<<dim3(512), dim3(512), 0, stream>>>(qkv, bias2, attn);
    out_mfma_kernel<<<dim3(512), dim3(512), 0, stream>>>(attn, Wt_out, bout, out);
}